// Round 7
// baseline (311.990 us; speedup 1.0000x reference)
//
#include <hip/hip_runtime.h>
#include <math.h>

typedef __bf16 bf16_t;
typedef __bf16 bf16x8 __attribute__((ext_vector_type(8)));
typedef float f32x4 __attribute__((ext_vector_type(4)));
typedef float f32x16 __attribute__((ext_vector_type(16)));

// async global->LDS, 16B per lane. Dest must be wave-uniform base; HW adds lane*16.
__device__ __forceinline__ void gload_lds16(const bf16_t* g, bf16_t* l) {
    __builtin_amdgcn_global_load_lds((const __attribute__((address_space(1))) void*)g,
                                     (__attribute__((address_space(3))) void*)l, 16, 0, 0);
}

// ---------------------------------------------------------------------------
// fused fp32 -> bf16 convert of x + 4 weights into ONE contiguous bf16 region.
// ---------------------------------------------------------------------------
__global__ __launch_bounds__(256) void cvt_all(const float* __restrict__ x,
                                               const float* __restrict__ wq,
                                               const float* __restrict__ wk,
                                               const float* __restrict__ wv,
                                               const float* __restrict__ wo,
                                               bf16_t* __restrict__ dst) {
    int c = blockIdx.x * 256 + threadIdx.x;
    const float* src;
    size_t off;
    if (c < 1048576) { src = x; off = c; }
    else {
        int q = (c - 1048576) >> 19;
        src = (q == 0) ? wq : (q == 1) ? wk : (q == 2) ? wv : wo;
        off = (c - 1048576) & 524287;
    }
    const float4* p = (const float4*)src + off * 2;
    float4 a = p[0], b = p[1];
    union { bf16_t h[8]; uint4 u; } pk;
    pk.h[0] = (bf16_t)a.x; pk.h[1] = (bf16_t)a.y; pk.h[2] = (bf16_t)a.z; pk.h[3] = (bf16_t)a.w;
    pk.h[4] = (bf16_t)b.x; pk.h[5] = (bf16_t)b.y; pk.h[6] = (bf16_t)b.z; pk.h[7] = (bf16_t)b.w;
    ((uint4*)dst)[c] = pk.u;
}

// ---------------------------------------------------------------------------
// GEMM: 256x128 tile, BK=64, 8 waves (4Mx2N, 64x64/wave), triple-buffered LDS,
// counted vmcnt(6), ONE barrier per K-tile. NO mid-tile fences: the compiler's
// own fine-grained lgkmcnt scheduling interleaves ds_read with MFMA (m97/m141:
// manual lgkmcnt(0)+sched_barrier pinning was the round-6 35%-MfmaUtil cap).
// T2 XOR swizzle (chunk ^= row&7) via pre-swizzled global source.
// MODE: 0 = bf16 C row-major; 1 = f32 C + bias; 2 = V -> Vt[B,H,128,S] fused.
// ---------------------------------------------------------------------------
template <int MODE, typename OutT>
__device__ __forceinline__ void gemm_core(bf16_t* __restrict__ AsB, bf16_t* __restrict__ BsB,
                                          const bf16_t* __restrict__ A,
                                          const bf16_t* __restrict__ Bm,
                                          const float* __restrict__ bias,
                                          OutT* __restrict__ C, bf16_t* __restrict__ Vt,
                                          int M, int N, int K, int bx, int by) {
    const int tid = threadIdx.x;
    const int w = tid >> 6, l = tid & 63;
    const int l16 = l & 15, lg = l >> 4;
    const int wr = w >> 1, wc = w & 1;
    const int m0 = bx * 256, n0 = by * 128;
    const int lsw = l16 & 7;

    f32x4 acc[4][4] = {};

    auto stageA = [&](int k0, int buf) {
#pragma unroll
        for (int j = 0; j < 4; ++j) {
            int c = tid + j * 512;
            int row = c >> 3;
            int kc = (c & 7) ^ (row & 7);
            gload_lds16(A + (size_t)(m0 + row) * K + k0 + kc * 8,
                        &AsB[buf * 16384 + (j * 512 + w * 64) * 8]);
        }
    };
    auto stageB = [&](int k0, int buf) {
#pragma unroll
        for (int j = 0; j < 2; ++j) {
            int c = tid + j * 512;
            int row = c >> 3;
            int kc = (c & 7) ^ (row & 7);
            gload_lds16(Bm + (size_t)(n0 + row) * K + k0 + kc * 8,
                        &BsB[buf * 8192 + (j * 512 + w * 64) * 8]);
        }
    };

    stageA(0, 0); stageB(0, 0);
    stageA(64, 1); stageB(64, 1);
    asm volatile("s_waitcnt vmcnt(6)" ::: "memory");  // tile 0 landed
    __builtin_amdgcn_s_barrier();

    const int nt = K / 64;
    int cur = 0;
    for (int t = 0; t < nt; ++t) {
        int nxt = cur + 2; if (nxt >= 3) nxt -= 3;
        const bool pf = (t + 2 < nt);
        const int k2 = (t + 2) * 64;
        const bf16_t* Asc = &AsB[cur * 16384];
        const bf16_t* Bsc = &BsB[cur * 8192];

        // issue next-next tile's staging FIRST (in flight across this tile)
        if (pf) { stageA(k2, nxt); stageB(k2, nxt); }

        // read all fragments; compiler interleaves counted lgkm waits w/ MFMA
        bf16x8 af[4][2], bfr[4][2];
#pragma unroll
        for (int mf = 0; mf < 4; ++mf)
#pragma unroll
            for (int ks = 0; ks < 2; ++ks) {
                int arow = wr * 64 + mf * 16 + l16;
                af[mf][ks] = *(const bf16x8*)&Asc[arow * 64 + (((ks << 2) | lg) ^ lsw) * 8];
            }
#pragma unroll
        for (int nf = 0; nf < 4; ++nf)
#pragma unroll
            for (int ks = 0; ks < 2; ++ks) {
                int brow = wc * 64 + nf * 16 + l16;
                bfr[nf][ks] = *(const bf16x8*)&Bsc[brow * 64 + (((ks << 2) | lg) ^ lsw) * 8];
            }
#pragma unroll
        for (int ks = 0; ks < 2; ++ks)
#pragma unroll
            for (int mf = 0; mf < 4; ++mf)
#pragma unroll
                for (int nf = 0; nf < 4; ++nf)
                    acc[mf][nf] = __builtin_amdgcn_mfma_f32_16x16x32_bf16(af[mf][ks], bfr[nf][ks], acc[mf][nf], 0, 0, 0);

        // tile boundary: counted wait (tile t+1 landed), one barrier
        if (pf) asm volatile("s_waitcnt vmcnt(6)" ::: "memory");
        else    asm volatile("s_waitcnt vmcnt(0)" ::: "memory");
        __builtin_amdgcn_s_barrier();
        cur = (cur + 1 == 3) ? 0 : cur + 1;
    }

    if constexpr (MODE == 2) {
#pragma unroll
        for (int mf = 0; mf < 4; ++mf)
#pragma unroll
            for (int nf = 0; nf < 4; ++nf) {
                int col = n0 + wc * 64 + nf * 16 + l16;
                int hh = col >> 7, dh = col & 127;
                int rowbase = m0 + wr * 64 + mf * 16 + lg * 4;
                int bb = rowbase >> 11, s = rowbase & 2047;
                union { bf16_t h[4]; ushort4 u4; } pk;
#pragma unroll
                for (int r = 0; r < 4; ++r) pk.h[r] = (bf16_t)acc[mf][nf][r];
                *(ushort4*)&Vt[(((size_t)(bb * 16 + hh)) * 128 + dh) * 2048 + s] = pk.u4;
            }
    } else {
#pragma unroll
        for (int mf = 0; mf < 4; ++mf)
#pragma unroll
            for (int nf = 0; nf < 4; ++nf) {
                int col = n0 + wc * 64 + nf * 16 + l16;
                float bv = (MODE == 1) ? bias[col] : 0.f;
#pragma unroll
                for (int r = 0; r < 4; ++r) {
                    int row = m0 + wr * 64 + mf * 16 + lg * 4 + r;
                    C[(size_t)row * N + col] = (OutT)(acc[mf][nf][r] + bv);
                }
            }
    }
}

__global__ __launch_bounds__(512, 2) void gemm_qkv(const bf16_t* __restrict__ A,
                                                   const bf16_t* __restrict__ W0,
                                                   const bf16_t* __restrict__ W1,
                                                   const bf16_t* __restrict__ W2,
                                                   bf16_t* __restrict__ O0, bf16_t* __restrict__ O1,
                                                   bf16_t* __restrict__ Vt, int M, int N, int K) {
    __shared__ __align__(16) bf16_t As[3 * 256 * 64];
    __shared__ __align__(16) bf16_t Bs[3 * 128 * 64];
    int flat = blockIdx.x + 16 * (blockIdx.y + 16 * blockIdx.z);
    int idx = (flat & 7) * 96 + (flat >> 3);
    int bx = idx & 15, by = (idx >> 4) & 15, bz = idx >> 8;
    if (bz == 0)      gemm_core<0, bf16_t>(As, Bs, A, W0, nullptr, O0, nullptr, M, N, K, bx, by);
    else if (bz == 1) gemm_core<0, bf16_t>(As, Bs, A, W1, nullptr, O1, nullptr, M, N, K, bx, by);
    else              gemm_core<2, bf16_t>(As, Bs, A, W2, nullptr, (bf16_t*)nullptr, Vt, M, N, K, bx, by);
}

__global__ __launch_bounds__(512, 2) void gemm_bias_f32(const bf16_t* __restrict__ A,
                                                        const bf16_t* __restrict__ Bm,
                                                        const float* __restrict__ bias,
                                                        float* __restrict__ C, int M, int N, int K) {
    __shared__ __align__(16) bf16_t As[3 * 256 * 64];
    __shared__ __align__(16) bf16_t Bs[3 * 128 * 64];
    int flat = blockIdx.x + 16 * blockIdx.y;
    int idx = (flat & 7) * 32 + (flat >> 3);
    int bx = idx & 15, by = idx >> 4;
    gemm_core<1, float>(As, Bs, A, Bm, bias, C, nullptr, M, N, K, bx, by);
}

// ---------------------------------------------------------------------------
// Flash attention fwd, causal — swapped-operand 32x32 (validated round 6).
// ---------------------------------------------------------------------------
__global__ __launch_bounds__(512, 2) void attn_fwd(const bf16_t* __restrict__ Q,
                                                   const bf16_t* __restrict__ Kk,
                                                   const bf16_t* __restrict__ Vt,
                                                   bf16_t* __restrict__ Ctx, int S, int H) {
    const int D = H * 128;
    const int bh = blockIdx.x;
    const int qb = blockIdx.y;
    const int b = bh >> 4, h = bh & 15;
    const int tid = threadIdx.x;
    const int w = tid >> 6, l = tid & 63;
    const int l32 = l & 31, hi = l >> 5;
    const int q0w = qb * 256 + w * 32;
    const int qrow = q0w + l32;

    __shared__ __align__(16) bf16_t ks[2][64 * 128];
    __shared__ __align__(16) bf16_t vs[2][128 * 64];

    bf16x8 qf[8];
    {
        const bf16_t* qp = Q + (size_t)(b * S + qrow) * D + h * 128 + hi * 8;
#pragma unroll
        for (int d = 0; d < 8; ++d) qf[d] = *(const bf16x8*)(qp + d * 16);
    }

    f32x16 ctx[4] = {};
    float mrun = -INFINITY, lrun = 0.f;
    const float Cs = 0.08838834764831845f * 1.4426950408889634f;

    auto stage = [&](int k0, int buf) {
#pragma unroll
        for (int j = 0; j < 2; ++j) {
            int c = tid + j * 512;
            int r = c >> 4;
            int c16 = (c & 15) ^ (r & 7);
            gload_lds16(Kk + (size_t)(b * S + k0 + r) * D + h * 128 + c16 * 8,
                        &ks[buf][(j * 512 + w * 64) * 8]);
            int dd = c >> 3;
            int k8 = (c & 7) ^ (dd & 7);
            gload_lds16(Vt + ((size_t)bh * 128 + dd) * S + k0 + k8 * 8,
                        &vs[buf][(j * 512 + w * 64) * 8]);
        }
    };

    stage(0, 0);
    const int nkt = 4 * qb + 4;
    int cur = 0;
    for (int kt = 0; kt < nkt; ++kt) {
        __syncthreads();
        if (kt + 1 < nkt) stage((kt + 1) * 64, cur ^ 1);
        const int k0 = kt * 64;
        if (k0 <= q0w + 31) {
            f32x16 sacc[2] = {};
#pragma unroll
            for (int d = 0; d < 8; ++d) {
#pragma unroll
                for (int t2 = 0; t2 < 2; ++t2) {
                    int row = t2 * 32 + l32;
                    int c16 = (2 * d + hi) ^ (row & 7);
                    bf16x8 kf = *(const bf16x8*)&ks[cur][(row * 16 + c16) * 8];
                    sacc[t2] = __builtin_amdgcn_mfma_f32_32x32x16_bf16(kf, qf[d], sacc[t2], 0, 0, 0);
                }
            }
            const bool diag = (k0 + 63 > q0w);
#pragma unroll
            for (int t2 = 0; t2 < 2; ++t2)
#pragma unroll
                for (int c = 0; c < 16; ++c) {
                    float s = sacc[t2][c] * Cs;
                    if (diag) {
                        int key = k0 + 32 * t2 + (c & 3) + 8 * (c >> 2) + 4 * hi;
                        if (key > qrow) s = -INFINITY;
                    }
                    sacc[t2][c] = s;
                }
            float tm[16];
#pragma unroll
            for (int c = 0; c < 16; ++c) tm[c] = fmaxf(sacc[0][c], sacc[1][c]);
#pragma unroll
            for (int sft = 8; sft; sft >>= 1)
#pragma unroll
                for (int c = 0; c < 8; ++c)
                    if (c < sft) tm[c] = fmaxf(tm[c], tm[c + sft]);
            float pmax = fmaxf(tm[0], __shfl_xor(tm[0], 32));
            if (!__all(pmax <= mrun + 8.f)) {
                float mnew = fmaxf(mrun, pmax);
                float alpha = exp2f(mrun - mnew);
                lrun *= alpha;
#pragma unroll
                for (int dblk = 0; dblk < 4; ++dblk)
#pragma unroll
                    for (int c = 0; c < 16; ++c) ctx[dblk][c] *= alpha;
                mrun = mnew;
            }
#pragma unroll
            for (int t2 = 0; t2 < 2; ++t2)
#pragma unroll
                for (int c = 0; c < 16; ++c) sacc[t2][c] = exp2f(sacc[t2][c] - mrun);
            float ts[16];
#pragma unroll
            for (int c = 0; c < 16; ++c) ts[c] = sacc[0][c] + sacc[1][c];
#pragma unroll
            for (int sft = 8; sft; sft >>= 1)
#pragma unroll
                for (int c = 0; c < 8; ++c)
                    if (c < sft) ts[c] += ts[c + sft];
            lrun += ts[0] + __shfl_xor(ts[0], 32);
            bf16x8 pa[4];
#pragma unroll
            for (int ksx = 0; ksx < 4; ++ksx) {
                const int t2 = ksx >> 1, cb = (ksx & 1) * 8;
                union { bf16_t hh[4]; unsigned u[2]; } Wlo, Whi;
#pragma unroll
                for (int i = 0; i < 4; ++i) {
                    Wlo.hh[i] = (bf16_t)sacc[t2][cb + i];
                    Whi.hh[i] = (bf16_t)sacc[t2][cb + 4 + i];
                }
                unsigned s0 = hi ? Wlo.u[0] : Whi.u[0];
                unsigned s1 = hi ? Wlo.u[1] : Whi.u[1];
                unsigned r0 = __shfl_xor(s0, 32);
                unsigned r1 = __shfl_xor(s1, 32);
                union { unsigned u[4]; bf16x8 v; } F;
                if (hi == 0) { F.u[0] = Wlo.u[0]; F.u[1] = Wlo.u[1]; F.u[2] = r0; F.u[3] = r1; }
                else         { F.u[0] = r0; F.u[1] = r1; F.u[2] = Whi.u[0]; F.u[3] = Whi.u[1]; }
                pa[ksx] = F.v;
            }
#pragma unroll
            for (int ksx = 0; ksx < 4; ++ksx)
#pragma unroll
                for (int dblk = 0; dblk < 4; ++dblk) {
                    int dd = dblk * 32 + l32;
                    int k8 = (2 * ksx + hi) ^ (dd & 7);
                    bf16x8 vf = *(const bf16x8*)&vs[cur][(dd * 8 + k8) * 8];
                    ctx[dblk] = __builtin_amdgcn_mfma_f32_32x32x16_bf16(vf, pa[ksx], ctx[dblk], 0, 0, 0);
                }
        }
        cur ^= 1;
    }
    float invl = 1.f / lrun;
    bf16_t* op = Ctx + (size_t)(b * S + qrow) * D + h * 128;
#pragma unroll
    for (int dblk = 0; dblk < 4; ++dblk)
#pragma unroll
        for (int cg = 0; cg < 4; ++cg) {
            union { bf16_t hh[4]; ushort4 u4; } pk;
#pragma unroll
            for (int i = 0; i < 4; ++i) pk.hh[i] = (bf16_t)(ctx[dblk][cg * 4 + i] * invl);
            *(ushort4*)&op[dblk * 32 + cg * 8 + hi * 4] = pk.u4;
        }
}

// ---------------------------------------------------------------------------
extern "C" void kernel_launch(void* const* d_in, const int* in_sizes, int n_in,
                              void* d_out, int out_size, void* d_ws, size_t ws_size,
                              hipStream_t stream) {
    const int B = 2, S = 2048, D = 2048, H = 16;
    const int M = B * S;
    const float* x  = (const float*)d_in[0];
    const float* wq = (const float*)d_in[1];
    const float* wk = (const float*)d_in[2];
    const float* wv = (const float*)d_in[3];
    const float* wo = (const float*)d_in[4];
    const float* bo = (const float*)d_in[5];
    float* out = (float*)d_out;

    char* ws = (char*)d_ws;
    const size_t MB = 1024 * 1024;
    if (ws_size < 128 * MB) return;
    bf16_t* xb  = (bf16_t*)(ws);
    bf16_t* wqb = (bf16_t*)(ws + 16 * MB);
    bf16_t* wkb = (bf16_t*)(ws + 24 * MB);
    bf16_t* wvb = (bf16_t*)(ws + 32 * MB);
    bf16_t* wob = (bf16_t*)(ws + 40 * MB);
    bf16_t* qb  = (bf16_t*)(ws + 48 * MB);
    bf16_t* kb  = (bf16_t*)(ws + 64 * MB);
    bf16_t* vtb = (bf16_t*)(ws + 80 * MB);
    bf16_t* cxb = (bf16_t*)(ws + 96 * MB);

    cvt_all<<<12288, 256, 0, stream>>>(x, wq, wk, wv, wo, xb);
    gemm_qkv<<<dim3(16, 16, 3), 512, 0, stream>>>(xb, wqb, wkb, wvb, qb, kb, vtb, M, D, D);
    attn_fwd<<<dim3(32, 8), 512, 0, stream>>>(qb, kb, vtb, cxb, S, H);
    gemm_bias_f32<<<dim3(16, 16), 512, 0, stream>>>(cxb, wob, bo, out, M, D, D);
}

// Round 8
// 282.477 us; speedup vs baseline: 1.1045x; 1.1045x over previous
//
#include <hip/hip_runtime.h>
#include <math.h>

typedef __bf16 bf16_t;
typedef __bf16 bf16x8 __attribute__((ext_vector_type(8)));
typedef float f32x4 __attribute__((ext_vector_type(4)));
typedef float f32x16 __attribute__((ext_vector_type(16)));

// async global->LDS, 16B per lane. Dest must be wave-uniform base; HW adds lane*16.
__device__ __forceinline__ void gload_lds16(const bf16_t* g, bf16_t* l) {
    __builtin_amdgcn_global_load_lds((const __attribute__((address_space(1))) void*)g,
                                     (__attribute__((address_space(3))) void*)l, 16, 0, 0);
}

// ---------------------------------------------------------------------------
// fused fp32 -> bf16 convert of x + 4 weights into ONE contiguous bf16 region.
// ---------------------------------------------------------------------------
__global__ __launch_bounds__(256) void cvt_all(const float* __restrict__ x,
                                               const float* __restrict__ wq,
                                               const float* __restrict__ wk,
                                               const float* __restrict__ wv,
                                               const float* __restrict__ wo,
                                               bf16_t* __restrict__ dst) {
    int c = blockIdx.x * 256 + threadIdx.x;
    const float* src;
    size_t off;
    if (c < 1048576) { src = x; off = c; }
    else {
        int q = (c - 1048576) >> 19;
        src = (q == 0) ? wq : (q == 1) ? wk : (q == 2) ? wv : wo;
        off = (c - 1048576) & 524287;
    }
    const float4* p = (const float4*)src + off * 2;
    float4 a = p[0], b = p[1];
    union { bf16_t h[8]; uint4 u; } pk;
    pk.h[0] = (bf16_t)a.x; pk.h[1] = (bf16_t)a.y; pk.h[2] = (bf16_t)a.z; pk.h[3] = (bf16_t)a.w;
    pk.h[4] = (bf16_t)b.x; pk.h[5] = (bf16_t)b.y; pk.h[6] = (bf16_t)b.z; pk.h[7] = (bf16_t)b.w;
    ((uint4*)dst)[c] = pk.u;
}

// ---------------------------------------------------------------------------
// GEMM: 256x128 tile, BK=64, 8 waves (4Mx2N, 64x64/wave), triple-buffered LDS,
// counted vmcnt(6), setprio (R6-validated, 126us/35% MfmaUtil) + m201's
// pre-barrier: per phase {ds_reads; stage-issue; s_barrier; lgkmcnt(0);
// sched_barrier; prio1; 16 MFMA; prio0}. The pre-barrier clusters all waves'
// read-issue so LDS latency drains across barrier-arrival skew (m201: 62%).
// Raw s_barrier does NOT drain vmcnt -> prefetches stay in flight (T4).
// T2 XOR swizzle (chunk ^= row&7) via pre-swizzled global source.
// MODE: 0 = bf16 C row-major; 1 = f32 C + bias; 2 = V -> Vt[B,H,128,S] fused.
// ---------------------------------------------------------------------------
template <int MODE, typename OutT>
__device__ __forceinline__ void gemm_core(bf16_t* __restrict__ AsB, bf16_t* __restrict__ BsB,
                                          const bf16_t* __restrict__ A,
                                          const bf16_t* __restrict__ Bm,
                                          const float* __restrict__ bias,
                                          OutT* __restrict__ C, bf16_t* __restrict__ Vt,
                                          int M, int N, int K, int bx, int by) {
    const int tid = threadIdx.x;
    const int w = tid >> 6, l = tid & 63;
    const int l16 = l & 15, lg = l >> 4;
    const int wr = w >> 1, wc = w & 1;
    const int m0 = bx * 256, n0 = by * 128;
    const int lsw = l16 & 7;

    f32x4 acc[4][4] = {};

    auto stageA = [&](int k0, int buf) {
#pragma unroll
        for (int j = 0; j < 4; ++j) {
            int c = tid + j * 512;
            int row = c >> 3;
            int kc = (c & 7) ^ (row & 7);
            gload_lds16(A + (size_t)(m0 + row) * K + k0 + kc * 8,
                        &AsB[buf * 16384 + (j * 512 + w * 64) * 8]);
        }
    };
    auto stageB = [&](int k0, int buf) {
#pragma unroll
        for (int j = 0; j < 2; ++j) {
            int c = tid + j * 512;
            int row = c >> 3;
            int kc = (c & 7) ^ (row & 7);
            gload_lds16(Bm + (size_t)(n0 + row) * K + k0 + kc * 8,
                        &BsB[buf * 8192 + (j * 512 + w * 64) * 8]);
        }
    };

    stageA(0, 0); stageB(0, 0);
    stageA(64, 1); stageB(64, 1);
    asm volatile("s_waitcnt vmcnt(6)" ::: "memory");  // tile 0 landed
    __builtin_amdgcn_s_barrier();

    const int nt = K / 64;
    int cur = 0;
    for (int t = 0; t < nt; ++t) {
        int nxt = cur + 2; if (nxt >= 3) nxt -= 3;
        const bool pf = (t + 2 < nt);
        const int k2 = (t + 2) * 64;
        const bf16_t* Asc = &AsB[cur * 16384];
        const bf16_t* Bsc = &BsB[cur * 8192];

        // ---- phase 0: all B frags + A frags mf=0,1 ; stage A(t+2) ----
        bf16x8 bfr[4][2], af[2][2];
#pragma unroll
        for (int nf = 0; nf < 4; ++nf)
#pragma unroll
            for (int ks = 0; ks < 2; ++ks) {
                int brow = wc * 64 + nf * 16 + l16;
                bfr[nf][ks] = *(const bf16x8*)&Bsc[brow * 64 + (((ks << 2) | lg) ^ lsw) * 8];
            }
#pragma unroll
        for (int i = 0; i < 2; ++i)
#pragma unroll
            for (int ks = 0; ks < 2; ++ks) {
                int arow = wr * 64 + i * 16 + l16;
                af[i][ks] = *(const bf16x8*)&Asc[arow * 64 + (((ks << 2) | lg) ^ lsw) * 8];
            }
        if (pf) stageA(k2, nxt);
        __builtin_amdgcn_s_barrier();                      // m201 pre-barrier
        asm volatile("s_waitcnt lgkmcnt(0)" ::: "memory");
        __builtin_amdgcn_sched_barrier(0);                 // rule #18
        __builtin_amdgcn_s_setprio(1);
#pragma unroll
        for (int ks = 0; ks < 2; ++ks)
#pragma unroll
            for (int i = 0; i < 2; ++i)
#pragma unroll
                for (int nf = 0; nf < 4; ++nf)
                    acc[i][nf] = __builtin_amdgcn_mfma_f32_16x16x32_bf16(af[i][ks], bfr[nf][ks], acc[i][nf], 0, 0, 0);
        __builtin_amdgcn_s_setprio(0);

        // ---- phase 1: A frags mf=2,3 (B held in regs) ; stage B(t+2) ----
        bf16x8 af2[2][2];
#pragma unroll
        for (int i = 0; i < 2; ++i)
#pragma unroll
            for (int ks = 0; ks < 2; ++ks) {
                int arow = wr * 64 + (i + 2) * 16 + l16;
                af2[i][ks] = *(const bf16x8*)&Asc[arow * 64 + (((ks << 2) | lg) ^ lsw) * 8];
            }
        if (pf) stageB(k2, nxt);
        __builtin_amdgcn_s_barrier();                      // m201 pre-barrier
        asm volatile("s_waitcnt lgkmcnt(0)" ::: "memory");
        __builtin_amdgcn_sched_barrier(0);
        __builtin_amdgcn_s_setprio(1);
#pragma unroll
        for (int ks = 0; ks < 2; ++ks)
#pragma unroll
            for (int i = 0; i < 2; ++i)
#pragma unroll
                for (int nf = 0; nf < 4; ++nf)
                    acc[i + 2][nf] = __builtin_amdgcn_mfma_f32_16x16x32_bf16(af2[i][ks], bfr[nf][ks], acc[i + 2][nf], 0, 0, 0);
        __builtin_amdgcn_s_setprio(0);

        // ---- tile boundary: counted wait (tile t+1 landed), one barrier ----
        if (pf) asm volatile("s_waitcnt vmcnt(6)" ::: "memory");
        else    asm volatile("s_waitcnt vmcnt(0)" ::: "memory");
        __builtin_amdgcn_s_barrier();
        cur = (cur + 1 == 3) ? 0 : cur + 1;
    }

    if constexpr (MODE == 2) {
#pragma unroll
        for (int mf = 0; mf < 4; ++mf)
#pragma unroll
            for (int nf = 0; nf < 4; ++nf) {
                int col = n0 + wc * 64 + nf * 16 + l16;
                int hh = col >> 7, dh = col & 127;
                int rowbase = m0 + wr * 64 + mf * 16 + lg * 4;
                int bb = rowbase >> 11, s = rowbase & 2047;
                union { bf16_t h[4]; ushort4 u4; } pk;
#pragma unroll
                for (int r = 0; r < 4; ++r) pk.h[r] = (bf16_t)acc[mf][nf][r];
                *(ushort4*)&Vt[(((size_t)(bb * 16 + hh)) * 128 + dh) * 2048 + s] = pk.u4;
            }
    } else {
#pragma unroll
        for (int mf = 0; mf < 4; ++mf)
#pragma unroll
            for (int nf = 0; nf < 4; ++nf) {
                int col = n0 + wc * 64 + nf * 16 + l16;
                float bv = (MODE == 1) ? bias[col] : 0.f;
#pragma unroll
                for (int r = 0; r < 4; ++r) {
                    int row = m0 + wr * 64 + mf * 16 + lg * 4 + r;
                    C[(size_t)row * N + col] = (OutT)(acc[mf][nf][r] + bv);
                }
            }
    }
}

__global__ __launch_bounds__(512, 2) void gemm_qkv(const bf16_t* __restrict__ A,
                                                   const bf16_t* __restrict__ W0,
                                                   const bf16_t* __restrict__ W1,
                                                   const bf16_t* __restrict__ W2,
                                                   bf16_t* __restrict__ O0, bf16_t* __restrict__ O1,
                                                   bf16_t* __restrict__ Vt, int M, int N, int K) {
    __shared__ __align__(16) bf16_t As[3 * 256 * 64];
    __shared__ __align__(16) bf16_t Bs[3 * 128 * 64];
    int flat = blockIdx.x + 16 * (blockIdx.y + 16 * blockIdx.z);
    int idx = (flat & 7) * 96 + (flat >> 3);
    int bx = idx & 15, by = (idx >> 4) & 15, bz = idx >> 8;
    if (bz == 0)      gemm_core<0, bf16_t>(As, Bs, A, W0, nullptr, O0, nullptr, M, N, K, bx, by);
    else if (bz == 1) gemm_core<0, bf16_t>(As, Bs, A, W1, nullptr, O1, nullptr, M, N, K, bx, by);
    else              gemm_core<2, bf16_t>(As, Bs, A, W2, nullptr, (bf16_t*)nullptr, Vt, M, N, K, bx, by);
}

__global__ __launch_bounds__(512, 2) void gemm_bias_f32(const bf16_t* __restrict__ A,
                                                        const bf16_t* __restrict__ Bm,
                                                        const float* __restrict__ bias,
                                                        float* __restrict__ C, int M, int N, int K) {
    __shared__ __align__(16) bf16_t As[3 * 256 * 64];
    __shared__ __align__(16) bf16_t Bs[3 * 128 * 64];
    int flat = blockIdx.x + 16 * blockIdx.y;
    int idx = (flat & 7) * 32 + (flat >> 3);
    int bx = idx & 15, by = idx >> 4;
    gemm_core<1, float>(As, Bs, A, Bm, bias, C, nullptr, M, N, K, bx, by);
}

// ---------------------------------------------------------------------------
// Flash attention fwd, causal — swapped-operand 32x32 (validated round 6).
// ---------------------------------------------------------------------------
__global__ __launch_bounds__(512, 2) void attn_fwd(const bf16_t* __restrict__ Q,
                                                   const bf16_t* __restrict__ Kk,
                                                   const bf16_t* __restrict__ Vt,
                                                   bf16_t* __restrict__ Ctx, int S, int H) {
    const int D = H * 128;
    const int bh = blockIdx.x;
    const int qb = blockIdx.y;
    const int b = bh >> 4, h = bh & 15;
    const int tid = threadIdx.x;
    const int w = tid >> 6, l = tid & 63;
    const int l32 = l & 31, hi = l >> 5;
    const int q0w = qb * 256 + w * 32;
    const int qrow = q0w + l32;

    __shared__ __align__(16) bf16_t ks[2][64 * 128];
    __shared__ __align__(16) bf16_t vs[2][128 * 64];

    bf16x8 qf[8];
    {
        const bf16_t* qp = Q + (size_t)(b * S + qrow) * D + h * 128 + hi * 8;
#pragma unroll
        for (int d = 0; d < 8; ++d) qf[d] = *(const bf16x8*)(qp + d * 16);
    }

    f32x16 ctx[4] = {};
    float mrun = -INFINITY, lrun = 0.f;
    const float Cs = 0.08838834764831845f * 1.4426950408889634f;

    auto stage = [&](int k0, int buf) {
#pragma unroll
        for (int j = 0; j < 2; ++j) {
            int c = tid + j * 512;
            int r = c >> 4;
            int c16 = (c & 15) ^ (r & 7);
            gload_lds16(Kk + (size_t)(b * S + k0 + r) * D + h * 128 + c16 * 8,
                        &ks[buf][(j * 512 + w * 64) * 8]);
            int dd = c >> 3;
            int k8 = (c & 7) ^ (dd & 7);
            gload_lds16(Vt + ((size_t)bh * 128 + dd) * S + k0 + k8 * 8,
                        &vs[buf][(j * 512 + w * 64) * 8]);
        }
    };

    stage(0, 0);
    const int nkt = 4 * qb + 4;
    int cur = 0;
    for (int kt = 0; kt < nkt; ++kt) {
        __syncthreads();
        if (kt + 1 < nkt) stage((kt + 1) * 64, cur ^ 1);
        const int k0 = kt * 64;
        if (k0 <= q0w + 31) {
            f32x16 sacc[2] = {};
#pragma unroll
            for (int d = 0; d < 8; ++d) {
#pragma unroll
                for (int t2 = 0; t2 < 2; ++t2) {
                    int row = t2 * 32 + l32;
                    int c16 = (2 * d + hi) ^ (row & 7);
                    bf16x8 kf = *(const bf16x8*)&ks[cur][(row * 16 + c16) * 8];
                    sacc[t2] = __builtin_amdgcn_mfma_f32_32x32x16_bf16(kf, qf[d], sacc[t2], 0, 0, 0);
                }
            }
            const bool diag = (k0 + 63 > q0w);
#pragma unroll
            for (int t2 = 0; t2 < 2; ++t2)
#pragma unroll
                for (int c = 0; c < 16; ++c) {
                    float s = sacc[t2][c] * Cs;
                    if (diag) {
                        int key = k0 + 32 * t2 + (c & 3) + 8 * (c >> 2) + 4 * hi;
                        if (key > qrow) s = -INFINITY;
                    }
                    sacc[t2][c] = s;
                }
            float tm[16];
#pragma unroll
            for (int c = 0; c < 16; ++c) tm[c] = fmaxf(sacc[0][c], sacc[1][c]);
#pragma unroll
            for (int sft = 8; sft; sft >>= 1)
#pragma unroll
                for (int c = 0; c < 8; ++c)
                    if (c < sft) tm[c] = fmaxf(tm[c], tm[c + sft]);
            float pmax = fmaxf(tm[0], __shfl_xor(tm[0], 32));
            if (!__all(pmax <= mrun + 8.f)) {
                float mnew = fmaxf(mrun, pmax);
                float alpha = exp2f(mrun - mnew);
                lrun *= alpha;
#pragma unroll
                for (int dblk = 0; dblk < 4; ++dblk)
#pragma unroll
                    for (int c = 0; c < 16; ++c) ctx[dblk][c] *= alpha;
                mrun = mnew;
            }
#pragma unroll
            for (int t2 = 0; t2 < 2; ++t2)
#pragma unroll
                for (int c = 0; c < 16; ++c) sacc[t2][c] = exp2f(sacc[t2][c] - mrun);
            float ts[16];
#pragma unroll
            for (int c = 0; c < 16; ++c) ts[c] = sacc[0][c] + sacc[1][c];
#pragma unroll
            for (int sft = 8; sft; sft >>= 1)
#pragma unroll
                for (int c = 0; c < 8; ++c)
                    if (c < sft) ts[c] += ts[c + sft];
            lrun += ts[0] + __shfl_xor(ts[0], 32);
            bf16x8 pa[4];
#pragma unroll
            for (int ksx = 0; ksx < 4; ++ksx) {
                const int t2 = ksx >> 1, cb = (ksx & 1) * 8;
                union { bf16_t hh[4]; unsigned u[2]; } Wlo, Whi;
#pragma unroll
                for (int i = 0; i < 4; ++i) {
                    Wlo.hh[i] = (bf16_t)sacc[t2][cb + i];
                    Whi.hh[i] = (bf16_t)sacc[t2][cb + 4 + i];
                }
                unsigned s0 = hi ? Wlo.u[0] : Whi.u[0];
                unsigned s1 = hi ? Wlo.u[1] : Whi.u[1];
                unsigned r0 = __shfl_xor(s0, 32);
                unsigned r1 = __shfl_xor(s1, 32);
                union { unsigned u[4]; bf16x8 v; } F;
                if (hi == 0) { F.u[0] = Wlo.u[0]; F.u[1] = Wlo.u[1]; F.u[2] = r0; F.u[3] = r1; }
                else         { F.u[0] = r0; F.u[1] = r1; F.u[2] = Whi.u[0]; F.u[3] = Whi.u[1]; }
                pa[ksx] = F.v;
            }
#pragma unroll
            for (int ksx = 0; ksx < 4; ++ksx)
#pragma unroll
                for (int dblk = 0; dblk < 4; ++dblk) {
                    int dd = dblk * 32 + l32;
                    int k8 = (2 * ksx + hi) ^ (dd & 7);
                    bf16x8 vf = *(const bf16x8*)&vs[cur][(dd * 8 + k8) * 8];
                    ctx[dblk] = __builtin_amdgcn_mfma_f32_32x32x16_bf16(vf, pa[ksx], ctx[dblk], 0, 0, 0);
                }
        }
        cur ^= 1;
    }
    float invl = 1.f / lrun;
    bf16_t* op = Ctx + (size_t)(b * S + qrow) * D + h * 128;
#pragma unroll
    for (int dblk = 0; dblk < 4; ++dblk)
#pragma unroll
        for (int cg = 0; cg < 4; ++cg) {
            union { bf16_t hh[4]; ushort4 u4; } pk;
#pragma unroll
            for (int i = 0; i < 4; ++i) pk.hh[i] = (bf16_t)(ctx[dblk][cg * 4 + i] * invl);
            *(ushort4*)&op[dblk * 32 + cg * 8 + hi * 4] = pk.u4;
        }
}

// ---------------------------------------------------------------------------
extern "C" void kernel_launch(void* const* d_in, const int* in_sizes, int n_in,
                              void* d_out, int out_size, void* d_ws, size_t ws_size,
                              hipStream_t stream) {
    const int B = 2, S = 2048, D = 2048, H = 16;
    const int M = B * S;
    const float* x  = (const float*)d_in[0];
    const float* wq = (const float*)d_in[1];
    const float* wk = (const float*)d_in[2];
    const float* wv = (const float*)d_in[3];
    const float* wo = (const float*)d_in[4];
    const float* bo = (const float*)d_in[5];
    float* out = (float*)d_out;

    char* ws = (char*)d_ws;
    const size_t MB = 1024 * 1024;
    if (ws_size < 128 * MB) return;
    bf16_t* xb  = (bf16_t*)(ws);
    bf16_t* wqb = (bf16_t*)(ws + 16 * MB);
    bf16_t* wkb = (bf16_t*)(ws + 24 * MB);
    bf16_t* wvb = (bf16_t*)(ws + 32 * MB);
    bf16_t* wob = (bf16_t*)(ws + 40 * MB);
    bf16_t* qb  = (bf16_t*)(ws + 48 * MB);
    bf16_t* kb  = (bf16_t*)(ws + 64 * MB);
    bf16_t* vtb = (bf16_t*)(ws + 80 * MB);
    bf16_t* cxb = (bf16_t*)(ws + 96 * MB);

    cvt_all<<<12288, 256, 0, stream>>>(x, wq, wk, wv, wo, xb);
    gemm_qkv<<<dim3(16, 16, 3), 512, 0, stream>>>(xb, wqb, wkb, wvb, qb, kb, vtb, M, D, D);
    attn_fwd<<<dim3(32, 8), 512, 0, stream>>>(qb, kb, vtb, cxb, S, H);
    gemm_bias_f32<<<dim3(16, 16), 512, 0, stream>>>(cxb, wob, bo, out, M, D, D);
}

// Round 9
// 252.242 us; speedup vs baseline: 1.2369x; 1.1199x over previous
//
#include <hip/hip_runtime.h>
#include <math.h>

typedef __bf16 bf16_t;
typedef __bf16 bf16x8 __attribute__((ext_vector_type(8)));
typedef float f32x4 __attribute__((ext_vector_type(4)));
typedef float f32x16 __attribute__((ext_vector_type(16)));

// async global->LDS, 16B per lane. Dest must be wave-uniform base; HW adds lane*16.
__device__ __forceinline__ void gload_lds16(const bf16_t* g, bf16_t* l) {
    __builtin_amdgcn_global_load_lds((const __attribute__((address_space(1))) void*)g,
                                     (__attribute__((address_space(3))) void*)l, 16, 0, 0);
}

// ---------------------------------------------------------------------------
// fused fp32 -> bf16 convert of x + 4 weights into ONE contiguous bf16 region.
// ---------------------------------------------------------------------------
__global__ __launch_bounds__(256) void cvt_all(const float* __restrict__ x,
                                               const float* __restrict__ wq,
                                               const float* __restrict__ wk,
                                               const float* __restrict__ wv,
                                               const float* __restrict__ wo,
                                               bf16_t* __restrict__ dst) {
    int c = blockIdx.x * 256 + threadIdx.x;
    const float* src;
    size_t off;
    if (c < 1048576) { src = x; off = c; }
    else {
        int q = (c - 1048576) >> 19;
        src = (q == 0) ? wq : (q == 1) ? wk : (q == 2) ? wv : wo;
        off = (c - 1048576) & 524287;
    }
    const float4* p = (const float4*)src + off * 2;
    float4 a = p[0], b = p[1];
    union { bf16_t h[8]; uint4 u; } pk;
    pk.h[0] = (bf16_t)a.x; pk.h[1] = (bf16_t)a.y; pk.h[2] = (bf16_t)a.z; pk.h[3] = (bf16_t)a.w;
    pk.h[4] = (bf16_t)b.x; pk.h[5] = (bf16_t)b.y; pk.h[6] = (bf16_t)b.z; pk.h[7] = (bf16_t)b.w;
    ((uint4*)dst)[c] = pk.u;
}

// ---------------------------------------------------------------------------
// GEMM (EXACT R6 core — best validated: 126us qkv, MfmaUtil 35%, conflicts 0).
// 256x128 tile, BK=64, 8 waves (4Mx2N), triple-buffered LDS, counted vmcnt(6),
// one barrier/K-tile, 2 fenced phases {reads; stage; lgkm(0); sched_barrier;
// prio1; 16 MFMA; prio0}. T2 swizzle via pre-swizzled global source.
// MODE: 0 = bf16 C; 1 = f32 C + bias; 2 = V -> Vt[B,H,128,S] fused.
// ---------------------------------------------------------------------------
template <int MODE, typename OutT>
__device__ __forceinline__ void gemm_core(bf16_t* __restrict__ AsB, bf16_t* __restrict__ BsB,
                                          const bf16_t* __restrict__ A,
                                          const bf16_t* __restrict__ Bm,
                                          const float* __restrict__ bias,
                                          OutT* __restrict__ C, bf16_t* __restrict__ Vt,
                                          int M, int N, int K, int bx, int by) {
    const int tid = threadIdx.x;
    const int w = tid >> 6, l = tid & 63;
    const int l16 = l & 15, lg = l >> 4;
    const int wr = w >> 1, wc = w & 1;
    const int m0 = bx * 256, n0 = by * 128;
    const int lsw = l16 & 7;

    f32x4 acc[4][4] = {};

    auto stageA = [&](int k0, int buf) {
#pragma unroll
        for (int j = 0; j < 4; ++j) {
            int c = tid + j * 512;
            int row = c >> 3;
            int kc = (c & 7) ^ (row & 7);
            gload_lds16(A + (size_t)(m0 + row) * K + k0 + kc * 8,
                        &AsB[buf * 16384 + (j * 512 + w * 64) * 8]);
        }
    };
    auto stageB = [&](int k0, int buf) {
#pragma unroll
        for (int j = 0; j < 2; ++j) {
            int c = tid + j * 512;
            int row = c >> 3;
            int kc = (c & 7) ^ (row & 7);
            gload_lds16(Bm + (size_t)(n0 + row) * K + k0 + kc * 8,
                        &BsB[buf * 8192 + (j * 512 + w * 64) * 8]);
        }
    };

    stageA(0, 0); stageB(0, 0);
    stageA(64, 1); stageB(64, 1);
    asm volatile("s_waitcnt vmcnt(6)" ::: "memory");  // tile 0 landed
    __builtin_amdgcn_s_barrier();

    const int nt = K / 64;
    int cur = 0;
    for (int t = 0; t < nt; ++t) {
        int nxt = cur + 2; if (nxt >= 3) nxt -= 3;
        const bool pf = (t + 2 < nt);
        const int k2 = (t + 2) * 64;
        const bf16_t* Asc = &AsB[cur * 16384];
        const bf16_t* Bsc = &BsB[cur * 8192];

        // ---- phase 0: all B frags + A frags mf=0,1 ; stage A(t+2) ----
        bf16x8 bfr[4][2], af[2][2];
#pragma unroll
        for (int nf = 0; nf < 4; ++nf)
#pragma unroll
            for (int ks = 0; ks < 2; ++ks) {
                int brow = wc * 64 + nf * 16 + l16;
                bfr[nf][ks] = *(const bf16x8*)&Bsc[brow * 64 + (((ks << 2) | lg) ^ lsw) * 8];
            }
#pragma unroll
        for (int i = 0; i < 2; ++i)
#pragma unroll
            for (int ks = 0; ks < 2; ++ks) {
                int arow = wr * 64 + i * 16 + l16;
                af[i][ks] = *(const bf16x8*)&Asc[arow * 64 + (((ks << 2) | lg) ^ lsw) * 8];
            }
        if (pf) stageA(k2, nxt);
        asm volatile("s_waitcnt lgkmcnt(0)" ::: "memory");
        __builtin_amdgcn_sched_barrier(0);
        __builtin_amdgcn_s_setprio(1);
#pragma unroll
        for (int ks = 0; ks < 2; ++ks)
#pragma unroll
            for (int i = 0; i < 2; ++i)
#pragma unroll
                for (int nf = 0; nf < 4; ++nf)
                    acc[i][nf] = __builtin_amdgcn_mfma_f32_16x16x32_bf16(af[i][ks], bfr[nf][ks], acc[i][nf], 0, 0, 0);
        __builtin_amdgcn_s_setprio(0);

        // ---- phase 1: A frags mf=2,3 (B held in regs) ; stage B(t+2) ----
        bf16x8 af2[2][2];
#pragma unroll
        for (int i = 0; i < 2; ++i)
#pragma unroll
            for (int ks = 0; ks < 2; ++ks) {
                int arow = wr * 64 + (i + 2) * 16 + l16;
                af2[i][ks] = *(const bf16x8*)&Asc[arow * 64 + (((ks << 2) | lg) ^ lsw) * 8];
            }
        if (pf) stageB(k2, nxt);
        asm volatile("s_waitcnt lgkmcnt(0)" ::: "memory");
        __builtin_amdgcn_sched_barrier(0);
        __builtin_amdgcn_s_setprio(1);
#pragma unroll
        for (int ks = 0; ks < 2; ++ks)
#pragma unroll
            for (int i = 0; i < 2; ++i)
#pragma unroll
                for (int nf = 0; nf < 4; ++nf)
                    acc[i + 2][nf] = __builtin_amdgcn_mfma_f32_16x16x32_bf16(af2[i][ks], bfr[nf][ks], acc[i + 2][nf], 0, 0, 0);
        __builtin_amdgcn_s_setprio(0);

        // ---- tile boundary: counted wait (tile t+1 landed), one barrier ----
        if (pf) asm volatile("s_waitcnt vmcnt(6)" ::: "memory");
        else    asm volatile("s_waitcnt vmcnt(0)" ::: "memory");
        __builtin_amdgcn_s_barrier();
        cur = (cur + 1 == 3) ? 0 : cur + 1;
    }

    if constexpr (MODE == 2) {
#pragma unroll
        for (int mf = 0; mf < 4; ++mf)
#pragma unroll
            for (int nf = 0; nf < 4; ++nf) {
                int col = n0 + wc * 64 + nf * 16 + l16;
                int hh = col >> 7, dh = col & 127;
                int rowbase = m0 + wr * 64 + mf * 16 + lg * 4;
                int bb = rowbase >> 11, s = rowbase & 2047;
                union { bf16_t h[4]; ushort4 u4; } pk;
#pragma unroll
                for (int r = 0; r < 4; ++r) pk.h[r] = (bf16_t)acc[mf][nf][r];
                *(ushort4*)&Vt[(((size_t)(bb * 16 + hh)) * 128 + dh) * 2048 + s] = pk.u4;
            }
    } else {
#pragma unroll
        for (int mf = 0; mf < 4; ++mf)
#pragma unroll
            for (int nf = 0; nf < 4; ++nf) {
                int col = n0 + wc * 64 + nf * 16 + l16;
                float bv = (MODE == 1) ? bias[col] : 0.f;
#pragma unroll
                for (int r = 0; r < 4; ++r) {
                    int row = m0 + wr * 64 + mf * 16 + lg * 4 + r;
                    C[(size_t)row * N + col] = (OutT)(acc[mf][nf][r] + bv);
                }
            }
    }
}

__global__ __launch_bounds__(512, 2) void gemm_qkv(const bf16_t* __restrict__ A,
                                                   const bf16_t* __restrict__ W0,
                                                   const bf16_t* __restrict__ W1,
                                                   const bf16_t* __restrict__ W2,
                                                   bf16_t* __restrict__ O0, bf16_t* __restrict__ O1,
                                                   bf16_t* __restrict__ Vt, int M, int N, int K) {
    __shared__ __align__(16) bf16_t As[3 * 256 * 64];
    __shared__ __align__(16) bf16_t Bs[3 * 128 * 64];
    int flat = blockIdx.x + 16 * (blockIdx.y + 16 * blockIdx.z);
    int idx = (flat & 7) * 96 + (flat >> 3);
    int bx = idx & 15, by = (idx >> 4) & 15, bz = idx >> 8;
    if (bz == 0)      gemm_core<0, bf16_t>(As, Bs, A, W0, nullptr, O0, nullptr, M, N, K, bx, by);
    else if (bz == 1) gemm_core<0, bf16_t>(As, Bs, A, W1, nullptr, O1, nullptr, M, N, K, bx, by);
    else              gemm_core<2, bf16_t>(As, Bs, A, W2, nullptr, (bf16_t*)nullptr, Vt, M, N, K, bx, by);
}

__global__ __launch_bounds__(512, 2) void gemm_bias_f32(const bf16_t* __restrict__ A,
                                                        const bf16_t* __restrict__ Bm,
                                                        const float* __restrict__ bias,
                                                        float* __restrict__ C, int M, int N, int K) {
    __shared__ __align__(16) bf16_t As[3 * 256 * 64];
    __shared__ __align__(16) bf16_t Bs[3 * 128 * 64];
    int flat = blockIdx.x + 16 * blockIdx.y;
    int idx = (flat & 7) * 32 + (flat >> 3);
    int bx = idx & 15, by = idx >> 4;
    gemm_core<1, float>(As, Bs, A, Bm, bias, C, nullptr, M, N, K, bx, by);
}

// ---------------------------------------------------------------------------
// Flash attention fwd, causal — swapped-operand 32x32 wave code (validated
// R6), rebalanced: 4 waves / 256 thr, Q-tile 128 -> 512 blocks @ 2 blocks/CU
// (LDS 64KB). blockIdx.y -> qt map [15..8, 0..7] pairs co-resident blocks to
// a constant 34 tiles/CU-slot-pair (fixes the 1.78x causal imbalance).
// ---------------------------------------------------------------------------
__global__ __launch_bounds__(256, 2) void attn_fwd(const bf16_t* __restrict__ Q,
                                                   const bf16_t* __restrict__ Kk,
                                                   const bf16_t* __restrict__ Vt,
                                                   bf16_t* __restrict__ Ctx, int S, int H) {
    const int D = H * 128;
    const int bh = blockIdx.x;
    const int y = blockIdx.y;
    const int qt = (y < 8) ? (15 - y) : (y - 8);   // big-qt blocks dispatch first
    const int b = bh >> 4, h = bh & 15;
    const int tid = threadIdx.x;
    const int w = tid >> 6, l = tid & 63;
    const int l32 = l & 31, hi = l >> 5;
    const int q0w = qt * 128 + w * 32;
    const int qrow = q0w + l32;

    __shared__ __align__(16) bf16_t ks[2][64 * 128];
    __shared__ __align__(16) bf16_t vs[2][128 * 64];

    bf16x8 qf[8];
    {
        const bf16_t* qp = Q + (size_t)(b * S + qrow) * D + h * 128 + hi * 8;
#pragma unroll
        for (int d = 0; d < 8; ++d) qf[d] = *(const bf16x8*)(qp + d * 16);
    }

    f32x16 ctx[4] = {};
    float mrun = -INFINITY, lrun = 0.f;
    const float Cs = 0.08838834764831845f * 1.4426950408889634f;

    // 1024 chunks per tile / 256 thr = 4 K-gloads + 4 V-gloads per thread
    auto stage = [&](int k0, int buf) {
#pragma unroll
        for (int j = 0; j < 4; ++j) {
            int c = tid + j * 256;
            int r = c >> 4;
            int c16 = (c & 15) ^ (r & 7);
            gload_lds16(Kk + (size_t)(b * S + k0 + r) * D + h * 128 + c16 * 8,
                        &ks[buf][(j * 256 + w * 64) * 8]);
            int dd = c >> 3;
            int k8 = (c & 7) ^ (dd & 7);
            gload_lds16(Vt + ((size_t)bh * 128 + dd) * S + k0 + k8 * 8,
                        &vs[buf][(j * 256 + w * 64) * 8]);
        }
    };

    stage(0, 0);
    const int nkt = 2 * qt + 2;
    int cur = 0;
    for (int kt = 0; kt < nkt; ++kt) {
        __syncthreads();
        if (kt + 1 < nkt) stage((kt + 1) * 64, cur ^ 1);
        const int k0 = kt * 64;
        if (k0 <= q0w + 31) {
            f32x16 sacc[2] = {};
#pragma unroll
            for (int d = 0; d < 8; ++d) {
#pragma unroll
                for (int t2 = 0; t2 < 2; ++t2) {
                    int row = t2 * 32 + l32;
                    int c16 = (2 * d + hi) ^ (row & 7);
                    bf16x8 kf = *(const bf16x8*)&ks[cur][(row * 16 + c16) * 8];
                    sacc[t2] = __builtin_amdgcn_mfma_f32_32x32x16_bf16(kf, qf[d], sacc[t2], 0, 0, 0);
                }
            }
            const bool diag = (k0 + 63 > q0w);
#pragma unroll
            for (int t2 = 0; t2 < 2; ++t2)
#pragma unroll
                for (int c = 0; c < 16; ++c) {
                    float s = sacc[t2][c] * Cs;
                    if (diag) {
                        int key = k0 + 32 * t2 + (c & 3) + 8 * (c >> 2) + 4 * hi;
                        if (key > qrow) s = -INFINITY;
                    }
                    sacc[t2][c] = s;
                }
            float tm[16];
#pragma unroll
            for (int c = 0; c < 16; ++c) tm[c] = fmaxf(sacc[0][c], sacc[1][c]);
#pragma unroll
            for (int sft = 8; sft; sft >>= 1)
#pragma unroll
                for (int c = 0; c < 8; ++c)
                    if (c < sft) tm[c] = fmaxf(tm[c], tm[c + sft]);
            float pmax = fmaxf(tm[0], __shfl_xor(tm[0], 32));
            if (!__all(pmax <= mrun + 8.f)) {
                float mnew = fmaxf(mrun, pmax);
                float alpha = exp2f(mrun - mnew);
                lrun *= alpha;
#pragma unroll
                for (int dblk = 0; dblk < 4; ++dblk)
#pragma unroll
                    for (int c = 0; c < 16; ++c) ctx[dblk][c] *= alpha;
                mrun = mnew;
            }
#pragma unroll
            for (int t2 = 0; t2 < 2; ++t2)
#pragma unroll
                for (int c = 0; c < 16; ++c) sacc[t2][c] = exp2f(sacc[t2][c] - mrun);
            float ts[16];
#pragma unroll
            for (int c = 0; c < 16; ++c) ts[c] = sacc[0][c] + sacc[1][c];
#pragma unroll
            for (int sft = 8; sft; sft >>= 1)
#pragma unroll
                for (int c = 0; c < 8; ++c)
                    if (c < sft) ts[c] += ts[c + sft];
            lrun += ts[0] + __shfl_xor(ts[0], 32);
            bf16x8 pa[4];
#pragma unroll
            for (int ksx = 0; ksx < 4; ++ksx) {
                const int t2 = ksx >> 1, cb = (ksx & 1) * 8;
                union { bf16_t hh[4]; unsigned u[2]; } Wlo, Whi;
#pragma unroll
                for (int i = 0; i < 4; ++i) {
                    Wlo.hh[i] = (bf16_t)sacc[t2][cb + i];
                    Whi.hh[i] = (bf16_t)sacc[t2][cb + 4 + i];
                }
                unsigned s0 = hi ? Wlo.u[0] : Whi.u[0];
                unsigned s1 = hi ? Wlo.u[1] : Whi.u[1];
                unsigned r0 = __shfl_xor(s0, 32);
                unsigned r1 = __shfl_xor(s1, 32);
                union { unsigned u[4]; bf16x8 v; } F;
                if (hi == 0) { F.u[0] = Wlo.u[0]; F.u[1] = Wlo.u[1]; F.u[2] = r0; F.u[3] = r1; }
                else         { F.u[0] = r0; F.u[1] = r1; F.u[2] = Whi.u[0]; F.u[3] = Whi.u[1]; }
                pa[ksx] = F.v;
            }
#pragma unroll
            for (int ksx = 0; ksx < 4; ++ksx)
#pragma unroll
                for (int dblk = 0; dblk < 4; ++dblk) {
                    int dd = dblk * 32 + l32;
                    int k8 = (2 * ksx + hi) ^ (dd & 7);
                    bf16x8 vf = *(const bf16x8*)&vs[cur][(dd * 8 + k8) * 8];
                    ctx[dblk] = __builtin_amdgcn_mfma_f32_32x32x16_bf16(vf, pa[ksx], ctx[dblk], 0, 0, 0);
                }
        }
        cur ^= 1;
    }
    float invl = 1.f / lrun;
    bf16_t* op = Ctx + (size_t)(b * S + qrow) * D + h * 128;
#pragma unroll
    for (int dblk = 0; dblk < 4; ++dblk)
#pragma unroll
        for (int cg = 0; cg < 4; ++cg) {
            union { bf16_t hh[4]; ushort4 u4; } pk;
#pragma unroll
            for (int i = 0; i < 4; ++i) pk.hh[i] = (bf16_t)(ctx[dblk][cg * 4 + i] * invl);
            *(ushort4*)&op[dblk * 32 + cg * 8 + hi * 4] = pk.u4;
        }
}

// ---------------------------------------------------------------------------
extern "C" void kernel_launch(void* const* d_in, const int* in_sizes, int n_in,
                              void* d_out, int out_size, void* d_ws, size_t ws_size,
                              hipStream_t stream) {
    const int B = 2, S = 2048, D = 2048, H = 16;
    const int M = B * S;
    const float* x  = (const float*)d_in[0];
    const float* wq = (const float*)d_in[1];
    const float* wk = (const float*)d_in[2];
    const float* wv = (const float*)d_in[3];
    const float* wo = (const float*)d_in[4];
    const float* bo = (const float*)d_in[5];
    float* out = (float*)d_out;

    char* ws = (char*)d_ws;
    const size_t MB = 1024 * 1024;
    if (ws_size < 128 * MB) return;
    bf16_t* xb  = (bf16_t*)(ws);
    bf16_t* wqb = (bf16_t*)(ws + 16 * MB);
    bf16_t* wkb = (bf16_t*)(ws + 24 * MB);
    bf16_t* wvb = (bf16_t*)(ws + 32 * MB);
    bf16_t* wob = (bf16_t*)(ws + 40 * MB);
    bf16_t* qb  = (bf16_t*)(ws + 48 * MB);
    bf16_t* kb  = (bf16_t*)(ws + 64 * MB);
    bf16_t* vtb = (bf16_t*)(ws + 80 * MB);
    bf16_t* cxb = (bf16_t*)(ws + 96 * MB);

    cvt_all<<<12288, 256, 0, stream>>>(x, wq, wk, wv, wo, xb);
    gemm_qkv<<<dim3(16, 16, 3), 512, 0, stream>>>(xb, wqb, wkb, wvb, qb, kb, vtb, M, D, D);
    attn_fwd<<<dim3(32, 16), 256, 0, stream>>>(qb, kb, vtb, cxb, S, H);
    gemm_bias_f32<<<dim3(16, 16), 512, 0, stream>>>(cxb, wob, bo, out, M, D, D);
}